// Round 1
// baseline (166.605 us; speedup 1.0000x reference)
//
#include <hip/hip_runtime.h>

#define SPATIAL_SCALE 0.0625f
#define P_OUT 7
#define OUTPUT_DIM 256
#define PART_SIZE 7
#define SAMPLE_PER_PART 4
#define TRANS_STD 0.1f

// One thread per output element, output-linear order (pw fastest) so stores
// are coalesced and a wave's gathers cluster spatially within one roi.
__global__ __launch_bounds__(256) void dpsroi_kernel(
    const float* __restrict__ data,
    const float* __restrict__ rois,
    const float* __restrict__ offset,
    float* __restrict__ out,
    int total)
{
    int idx = blockIdx.x * blockDim.x + threadIdx.x;
    if (idx >= total) return;

    const int P = P_OUT;
    const int C = OUTPUT_DIM;
    const int H = 128, W = 128;

    int pw = idx % P;
    int ph = (idx / P) % P;
    int c  = (idx / (P * P)) % C;
    int n  = idx / (P * P * C);

    // roi math — wave-uniform per n (broadcast loads)
    const float* roi = rois + n * 5;
    int   b   = (int)roi[0];
    float rsw = rintf(roi[1]) * SPATIAL_SCALE - 0.5f;
    float rsh = rintf(roi[2]) * SPATIAL_SCALE - 0.5f;
    float rew = (rintf(roi[3]) + 1.0f) * SPATIAL_SCALE - 0.5f;
    float reh = (rintf(roi[4]) + 1.0f) * SPATIAL_SCALE - 0.5f;
    float rw  = fmaxf(rew - rsw, 0.1f);
    float rh  = fmaxf(reh - rsh, 0.1f);
    float binw = rw * (1.0f / P);
    float binh = rh * (1.0f / P);
    float subw = binw * (1.0f / SAMPLE_PER_PART);
    float subh = binh * (1.0f / SAMPLE_PER_PART);

    // part_h == ph, part_w == pw (P == PART_SIZE == 7, verified fp32-exact)
    float tx = offset[(n * 2 + 0) * (PART_SIZE * PART_SIZE) + ph * PART_SIZE + pw] * TRANS_STD;
    float ty = offset[(n * 2 + 1) * (PART_SIZE * PART_SIZE) + ph * PART_SIZE + pw] * TRANS_STD;

    float wstart = (float)pw * binw + rsw + tx * rw;
    float hstart = (float)ph * binh + rsh + ty * rh;

    const float* dplane = data + (size_t)(b * C + c) * (H * W);

    float ssum  = 0.0f;
    float count = 0.0f;
    #pragma unroll
    for (int ihs = 0; ihs < SAMPLE_PER_PART; ++ihs) {
        float hh = hstart + (float)ihs * subh;
        #pragma unroll
        for (int iws = 0; iws < SAMPLE_PER_PART; ++iws) {
            float ww = wstart + (float)iws * subw;

            float valid = ((ww >= -0.5f) & (ww <= (float)W - 0.5f) &
                           (hh >= -0.5f) & (hh <= (float)H - 0.5f)) ? 1.0f : 0.0f;

            float wc = fminf(fmaxf(ww, 0.0f), (float)W - 1.0f);
            float hc = fminf(fmaxf(hh, 0.0f), (float)H - 1.0f);

            float y0f = floorf(hc), x0f = floorf(wc);
            float y1f = ceilf(hc),  x1f = ceilf(wc);
            float dy = hc - y0f, dx = wc - x0f;

            int y0 = (int)y0f, y1 = (int)y1f;
            int x0 = (int)x0f, x1 = (int)x1f;

            float v00 = dplane[y0 * W + x0];
            float v01 = dplane[y0 * W + x1];
            float v10 = dplane[y1 * W + x0];
            float v11 = dplane[y1 * W + x1];

            float val = (1.0f - dy) * (1.0f - dx) * v00
                      + (1.0f - dy) * dx          * v01
                      + dy          * (1.0f - dx) * v10
                      + dy          * dx          * v11;

            ssum  += val * valid;
            count += valid;
        }
    }

    out[idx] = (count > 0.0f) ? (ssum / fmaxf(count, 1.0f)) : 0.0f;
}

extern "C" void kernel_launch(void* const* d_in, const int* in_sizes, int n_in,
                              void* d_out, int out_size, void* d_ws, size_t ws_size,
                              hipStream_t stream) {
    const float* data   = (const float*)d_in[0];
    const float* rois   = (const float*)d_in[1];
    const float* offset = (const float*)d_in[2];
    float* out = (float*)d_out;

    int total = out_size;           // 128 * 256 * 7 * 7 = 1,605,632
    int block = 256;
    int grid  = (total + block - 1) / block;
    dpsroi_kernel<<<grid, block, 0, stream>>>(data, rois, offset, out, total);
}

// Round 4
// 111.229 us; speedup vs baseline: 1.4979x; 1.4979x over previous
//
#include <hip/hip_runtime.h>

#define SPATIAL_SCALE 0.0625f
#define P_OUT 7
#define OUTPUT_DIM 256
#define PART_SIZE 7
#define SAMPLE_PER_PART 4
#define TRANS_STD 0.1f

// ---------------------------------------------------------------------------
// Kernel 1: transpose data [B=2][C=256][S=16384] -> ws [B][S][C]
// Tiles of 32 channels x 128 spatial; float4 global loads AND stores.
// ---------------------------------------------------------------------------
#define TP_SP 133   // padded LDS row stride (floats); 133 mod 32 = 5, coprime
__global__ __launch_bounds__(256) void transpose_kernel(
    const float* __restrict__ in, float* __restrict__ outp)
{
    __shared__ float tile[32 * TP_SP];
    const int b  = blockIdx.z;
    const int st = blockIdx.x * 128;  // spatial tile base
    const int ct = blockIdx.y * 32;   // channel tile base
    const int tid = threadIdx.x;

    const float* inb  = in   + (size_t)b * 256 * 16384;
    float*       outb = outp + (size_t)b * 16384 * 256;

    // load: thread -> (sx = tid%32 float4-col, cy = tid/32), 4 rows each
    {
        const int sx = (tid & 31) * 4;
        const int cy = tid >> 5;
        #pragma unroll
        for (int k = 0; k < 4; ++k) {
            const int c_local = cy + 8 * k;
            const float4 v = *(const float4*)(inb + (size_t)(ct + c_local) * 16384 + st + sx);
            float* t = &tile[c_local * TP_SP + sx];
            t[0] = v.x; t[1] = v.y; t[2] = v.z; t[3] = v.w;
        }
    }
    __syncthreads();
    // store: thread -> (cq = tid%8 channel-quad, sl = tid/8), 4 spatials each
    {
        const int cq = (tid & 7) * 4;
        const int sl = tid >> 3;
        #pragma unroll
        for (int k = 0; k < 4; ++k) {
            const int s_local = sl + 32 * k;
            float4 v;
            v.x = tile[(cq + 0) * TP_SP + s_local];
            v.y = tile[(cq + 1) * TP_SP + s_local];
            v.z = tile[(cq + 2) * TP_SP + s_local];
            v.w = tile[(cq + 3) * TP_SP + s_local];
            *(float4*)(outb + (size_t)(st + s_local) * 256 + ct + cq) = v;
        }
    }
}

// ---------------------------------------------------------------------------
// Kernel 2: one wave per (n, ph, pw), 4 waves per block. Lane t handles
// channels 4t..4t+3 (float4). Each bilinear corner for 256 channels = one
// contiguous 1 KB wave read. Output staged to outT[n][bin][c] (coalesced);
// STORE_DIRECT=1 variant writes straight to out[n][c][bin] (scattered).
// ---------------------------------------------------------------------------
template <int STORE_DIRECT>
__global__ __launch_bounds__(256) void dpsroi_gather_kernel(
    const float* __restrict__ dataT,   // [B][H*W][C]
    const float* __restrict__ rois,
    const float* __restrict__ offset,
    float* __restrict__ outp)          // outT staging or final out
{
    const int P = P_OUT;
    const int C = OUTPUT_DIM;
    const int H = 128, W = 128;

    const int wid  = blockIdx.x * 4 + (threadIdx.x >> 6);  // global wave id
    const int lane = threadIdx.x & 63;
    const int bin  = wid % (P * P);
    const int n    = wid / (P * P);
    const int pw   = bin % P;
    const int ph   = bin / P;

    // roi math — wave-uniform (broadcast/scalar)
    const float* roi = rois + n * 5;
    const int   b   = (int)roi[0];
    const float rsw = rintf(roi[1]) * SPATIAL_SCALE - 0.5f;
    const float rsh = rintf(roi[2]) * SPATIAL_SCALE - 0.5f;
    const float rew = (rintf(roi[3]) + 1.0f) * SPATIAL_SCALE - 0.5f;
    const float reh = (rintf(roi[4]) + 1.0f) * SPATIAL_SCALE - 0.5f;
    const float rw  = fmaxf(rew - rsw, 0.1f);
    const float rh  = fmaxf(reh - rsh, 0.1f);
    const float binw = rw * (1.0f / P);
    const float binh = rh * (1.0f / P);
    const float subw = binw * (1.0f / SAMPLE_PER_PART);
    const float subh = binh * (1.0f / SAMPLE_PER_PART);

    // part_h == ph, part_w == pw (P == PART_SIZE == 7, fp32-exact)
    const float tx = offset[(n * 2 + 0) * (PART_SIZE * PART_SIZE) + ph * PART_SIZE + pw] * TRANS_STD;
    const float ty = offset[(n * 2 + 1) * (PART_SIZE * PART_SIZE) + ph * PART_SIZE + pw] * TRANS_STD;

    const float wstart = (float)pw * binw + rsw + tx * rw;
    const float hstart = (float)ph * binh + rsh + ty * rh;

    const float* base = dataT + (size_t)b * (H * W) * C + 4 * lane;

    float4 acc = make_float4(0.f, 0.f, 0.f, 0.f);
    float  count = 0.0f;

    #pragma unroll
    for (int ihs = 0; ihs < SAMPLE_PER_PART; ++ihs) {
        const float hh = hstart + (float)ihs * subh;
        #pragma unroll
        for (int iws = 0; iws < SAMPLE_PER_PART; ++iws) {
            const float ww = wstart + (float)iws * subw;

            const float valid = ((ww >= -0.5f) & (ww <= (float)W - 0.5f) &
                                 (hh >= -0.5f) & (hh <= (float)H - 0.5f)) ? 1.0f : 0.0f;

            const float wc = fminf(fmaxf(ww, 0.0f), (float)W - 1.0f);
            const float hc = fminf(fmaxf(hh, 0.0f), (float)H - 1.0f);

            const float y0f = floorf(hc), x0f = floorf(wc);
            const float y1f = ceilf(hc),  x1f = ceilf(wc);
            const float dy = hc - y0f, dx = wc - x0f;

            const int y0 = (int)y0f, y1 = (int)y1f;
            const int x0 = (int)x0f, x1 = (int)x1f;

            const float4 v00 = *(const float4*)(base + (size_t)(y0 * W + x0) * C);
            const float4 v01 = *(const float4*)(base + (size_t)(y0 * W + x1) * C);
            const float4 v10 = *(const float4*)(base + (size_t)(y1 * W + x0) * C);
            const float4 v11 = *(const float4*)(base + (size_t)(y1 * W + x1) * C);

            const float w00 = (1.0f - dy) * (1.0f - dx) * valid;
            const float w01 = (1.0f - dy) * dx          * valid;
            const float w10 = dy          * (1.0f - dx) * valid;
            const float w11 = dy          * dx          * valid;

            acc.x += w00 * v00.x + w01 * v01.x + w10 * v10.x + w11 * v11.x;
            acc.y += w00 * v00.y + w01 * v01.y + w10 * v10.y + w11 * v11.y;
            acc.z += w00 * v00.z + w01 * v01.z + w10 * v10.z + w11 * v11.z;
            acc.w += w00 * v00.w + w01 * v01.w + w10 * v10.w + w11 * v11.w;

            count += valid;
        }
    }

    const float scale = (count > 0.0f) ? (1.0f / fmaxf(count, 1.0f)) : 0.0f;
    acc.x *= scale; acc.y *= scale; acc.z *= scale; acc.w *= scale;

    if (STORE_DIRECT) {
        // out[n][c][ph][pw], c = 4*lane + k
        const int obase = n * C * (P * P) + ph * P + pw;
        const int c0 = 4 * lane;
        outp[obase + (c0 + 0) * (P * P)] = acc.x;
        outp[obase + (c0 + 1) * (P * P)] = acc.y;
        outp[obase + (c0 + 2) * (P * P)] = acc.z;
        outp[obase + (c0 + 3) * (P * P)] = acc.w;
    } else {
        // outT[n][bin][c] — contiguous 1 KB per wave
        *(float4*)(outp + ((size_t)(n * (P * P) + bin) * C) + 4 * lane) = acc;
    }
}

// ---------------------------------------------------------------------------
// Kernel 3: remap outT [n][49][256] -> out [n][256][49]. One block per n.
// LDS stride 257 kills bank conflicts on the transposed read.
// ---------------------------------------------------------------------------
__global__ __launch_bounds__(256) void remap_kernel(
    const float* __restrict__ outT, float* __restrict__ outp)
{
    __shared__ float lds[49 * 257];
    const int n = blockIdx.x;
    const int t = threadIdx.x;
    const int NB = P_OUT * P_OUT;              // 49
    const int TOT = NB * OUTPUT_DIM;           // 12544

    const float* src = outT + (size_t)n * TOT;
    float*       dst = outp + (size_t)n * TOT;

    #pragma unroll
    for (int j = 0; j < TOT / 256; ++j) {      // 49 iters
        const int f = t + 256 * j;             // f = bin*256 + c
        lds[f + (f >> 8)] = src[f];            // lds[bin*257 + c]
    }
    __syncthreads();
    #pragma unroll
    for (int j = 0; j < TOT / 256; ++j) {
        const int o = t + 256 * j;             // o = c*49 + bin
        const int c = o / NB;
        const int bin = o - c * NB;
        dst[o] = lds[bin * 257 + c];
    }
}

// ---------------------------------------------------------------------------
// Fallback (round-0): direct gather from NCHW layout, used if ws too small.
// ---------------------------------------------------------------------------
__global__ __launch_bounds__(256) void dpsroi_kernel_direct(
    const float* __restrict__ data,
    const float* __restrict__ rois,
    const float* __restrict__ offset,
    float* __restrict__ out,
    int total)
{
    int idx = blockIdx.x * blockDim.x + threadIdx.x;
    if (idx >= total) return;

    const int P = P_OUT;
    const int C = OUTPUT_DIM;
    const int H = 128, W = 128;

    int pw = idx % P;
    int ph = (idx / P) % P;
    int c  = (idx / (P * P)) % C;
    int n  = idx / (P * P * C);

    const float* roi = rois + n * 5;
    int   b   = (int)roi[0];
    float rsw = rintf(roi[1]) * SPATIAL_SCALE - 0.5f;
    float rsh = rintf(roi[2]) * SPATIAL_SCALE - 0.5f;
    float rew = (rintf(roi[3]) + 1.0f) * SPATIAL_SCALE - 0.5f;
    float reh = (rintf(roi[4]) + 1.0f) * SPATIAL_SCALE - 0.5f;
    float rw  = fmaxf(rew - rsw, 0.1f);
    float rh  = fmaxf(reh - rsh, 0.1f);
    float binw = rw / P, binh = rh / P;
    float subw = binw / SAMPLE_PER_PART, subh = binh / SAMPLE_PER_PART;

    float tx = offset[(n * 2 + 0) * (PART_SIZE * PART_SIZE) + ph * PART_SIZE + pw] * TRANS_STD;
    float ty = offset[(n * 2 + 1) * (PART_SIZE * PART_SIZE) + ph * PART_SIZE + pw] * TRANS_STD;

    float wstart = (float)pw * binw + rsw + tx * rw;
    float hstart = (float)ph * binh + rsh + ty * rh;

    const float* dplane = data + (size_t)(b * C + c) * (H * W);

    float ssum = 0.0f, count = 0.0f;
    #pragma unroll
    for (int ihs = 0; ihs < SAMPLE_PER_PART; ++ihs) {
        float hh = hstart + (float)ihs * subh;
        #pragma unroll
        for (int iws = 0; iws < SAMPLE_PER_PART; ++iws) {
            float ww = wstart + (float)iws * subw;
            float valid = ((ww >= -0.5f) & (ww <= (float)W - 0.5f) &
                           (hh >= -0.5f) & (hh <= (float)H - 0.5f)) ? 1.0f : 0.0f;
            float wc = fminf(fmaxf(ww, 0.0f), (float)W - 1.0f);
            float hc = fminf(fmaxf(hh, 0.0f), (float)H - 1.0f);
            float y0f = floorf(hc), x0f = floorf(wc);
            float y1f = ceilf(hc),  x1f = ceilf(wc);
            float dy = hc - y0f, dx = wc - x0f;
            int y0 = (int)y0f, y1 = (int)y1f;
            int x0 = (int)x0f, x1 = (int)x1f;
            float v00 = dplane[y0 * W + x0];
            float v01 = dplane[y0 * W + x1];
            float v10 = dplane[y1 * W + x0];
            float v11 = dplane[y1 * W + x1];
            float val = (1.0f - dy) * (1.0f - dx) * v00
                      + (1.0f - dy) * dx          * v01
                      + dy          * (1.0f - dx) * v10
                      + dy          * dx          * v11;
            ssum  += val * valid;
            count += valid;
        }
    }
    out[idx] = (count > 0.0f) ? (ssum / fmaxf(count, 1.0f)) : 0.0f;
}

extern "C" void kernel_launch(void* const* d_in, const int* in_sizes, int n_in,
                              void* d_out, int out_size, void* d_ws, size_t ws_size,
                              hipStream_t stream) {
    const float* data   = (const float*)d_in[0];
    const float* rois   = (const float*)d_in[1];
    const float* offset = (const float*)d_in[2];
    float* out = (float*)d_out;

    const size_t needT    = (size_t)2 * 256 * 128 * 128 * sizeof(float);      // 33.5 MB
    const size_t needFull = needT + (size_t)128 * 49 * 256 * sizeof(float);   // +6.4 MB

    const int nwaves = 128 * P_OUT * P_OUT;  // 6272

    if (ws_size >= needT) {
        float* dataT = (float*)d_ws;
        dim3 tgrid(16384 / 128, 256 / 32, 2);
        transpose_kernel<<<tgrid, 256, 0, stream>>>(data, dataT);

        if (ws_size >= needFull) {
            float* outT = (float*)((char*)d_ws + needT);
            dpsroi_gather_kernel<0><<<nwaves / 4, 256, 0, stream>>>(dataT, rois, offset, outT);
            remap_kernel<<<128, 256, 0, stream>>>(outT, out);
        } else {
            dpsroi_gather_kernel<1><<<nwaves / 4, 256, 0, stream>>>(dataT, rois, offset, out);
        }
    } else {
        int total = out_size;
        dpsroi_kernel_direct<<<(total + 255) / 256, 256, 0, stream>>>(data, rois, offset, out, total);
    }
}

// Round 5
// 105.151 us; speedup vs baseline: 1.5844x; 1.0578x over previous
//
#include <hip/hip_runtime.h>

#define SPATIAL_SCALE 0.0625f
#define P_OUT 7
#define OUTPUT_DIM 256
#define PART_SIZE 7
#define SAMPLE_PER_PART 4
#define TRANS_STD 0.1f

#define NROIS 128
#define NBINS (P_OUT * P_OUT)            // 49
#define NWAVES (NROIS * NBINS)           // 6272
#define GBLOCKS (NWAVES / 4)             // 1568 = 8 * 196

// Per-bin separable-weight parameters (96 B, 24 dwords).
struct BinParam {
    float wx[8];     // x-window weights, pre-scaled by 1/max(cX,1)
    float wy[8];     // y-window weights, pre-scaled by 1/max(cY,1)
    int   fx, fy;    // window origin (pixel coords)
    int   nx, ny;    // window extent (<= 8)
    int   b;         // batch index
    int   pad[3];
};

// ---------------------------------------------------------------------------
// Kernel 0: per-bin weight precompute. One thread per (n, bin).
// Bilinear over 4x4 samples is separable: weight(i,j -> y,x) = a_i(y)*b_j(x),
// validity = validY(i)*validX(j), count = cY*cX. The 1/count division is
// folded into the weight scales.
// ---------------------------------------------------------------------------
__global__ __launch_bounds__(256) void params_kernel(
    const float* __restrict__ rois,
    const float* __restrict__ offset,
    BinParam* __restrict__ prm)
{
    const int t = blockIdx.x * 256 + threadIdx.x;
    if (t >= NWAVES) return;
    const int bin = t % NBINS;
    const int n   = t / NBINS;
    const int pw  = bin % P_OUT;
    const int ph  = bin / P_OUT;

    const float* roi = rois + n * 5;
    const int   b   = (int)roi[0];
    const float rsw = rintf(roi[1]) * SPATIAL_SCALE - 0.5f;
    const float rsh = rintf(roi[2]) * SPATIAL_SCALE - 0.5f;
    const float rew = (rintf(roi[3]) + 1.0f) * SPATIAL_SCALE - 0.5f;
    const float reh = (rintf(roi[4]) + 1.0f) * SPATIAL_SCALE - 0.5f;
    const float rw  = fmaxf(rew - rsw, 0.1f);
    const float rh  = fmaxf(reh - rsh, 0.1f);
    const float binw = rw * (1.0f / P_OUT);
    const float binh = rh * (1.0f / P_OUT);
    const float subw = binw * (1.0f / SAMPLE_PER_PART);
    const float subh = binh * (1.0f / SAMPLE_PER_PART);

    // part_h == ph, part_w == pw (P == PART_SIZE == 7, fp32-exact)
    const float tx = offset[(n * 2 + 0) * (PART_SIZE * PART_SIZE) + ph * PART_SIZE + pw] * TRANS_STD;
    const float ty = offset[(n * 2 + 1) * (PART_SIZE * PART_SIZE) + ph * PART_SIZE + pw] * TRANS_STD;

    const float wstart = (float)pw * binw + rsw + tx * rw;
    const float hstart = (float)ph * binh + rsh + ty * rh;

    BinParam p;
    #pragma unroll
    for (int k = 0; k < 8; ++k) { p.wx[k] = 0.0f; p.wy[k] = 0.0f; }

    // ---- x axis ----
    {
        const float wc0 = fminf(fmaxf(wstart, 0.0f), 127.0f);
        const int F = (int)floorf(wc0);
        float cX = 0.0f;
        float W8[8] = {0,0,0,0,0,0,0,0};
        #pragma unroll
        for (int j = 0; j < SAMPLE_PER_PART; ++j) {
            const float w = wstart + (float)j * subw;
            const bool  v = (w >= -0.5f) && (w <= 127.5f);
            const float wc = fminf(fmaxf(w, 0.0f), 127.0f);
            const int f = (int)floorf(wc);
            const int c = (int)ceilf(wc);
            const float dx = wc - (float)f;
            if (v) {
                const int kf = min(max(f - F, 0), 7);
                const int kc = min(max(c - F, 0), 7);
                W8[kf] += 1.0f - dx;
                W8[kc] += dx;
                cX += 1.0f;
            }
        }
        const float wcL = fminf(fmaxf(wstart + 3.0f * subw, 0.0f), 127.0f);
        p.fx = F;
        p.nx = min((int)ceilf(wcL) - F + 1, 8);
        const float s = 1.0f / fmaxf(cX, 1.0f);
        #pragma unroll
        for (int k = 0; k < 8; ++k) p.wx[k] = W8[k] * s;
    }
    // ---- y axis ----
    {
        const float hc0 = fminf(fmaxf(hstart, 0.0f), 127.0f);
        const int F = (int)floorf(hc0);
        float cY = 0.0f;
        float W8[8] = {0,0,0,0,0,0,0,0};
        #pragma unroll
        for (int j = 0; j < SAMPLE_PER_PART; ++j) {
            const float h = hstart + (float)j * subh;
            const bool  v = (h >= -0.5f) && (h <= 127.5f);
            const float hc = fminf(fmaxf(h, 0.0f), 127.0f);
            const int f = (int)floorf(hc);
            const int c = (int)ceilf(hc);
            const float dy = hc - (float)f;
            if (v) {
                const int kf = min(max(f - F, 0), 7);
                const int kc = min(max(c - F, 0), 7);
                W8[kf] += 1.0f - dy;
                W8[kc] += dy;
                cY += 1.0f;
            }
        }
        const float hcL = fminf(fmaxf(hstart + 3.0f * subh, 0.0f), 127.0f);
        p.fy = F;
        p.ny = min((int)ceilf(hcL) - F + 1, 8);
        const float s = 1.0f / fmaxf(cY, 1.0f);
        #pragma unroll
        for (int k = 0; k < 8; ++k) p.wy[k] = W8[k] * s;
    }
    p.b = b;
    p.pad[0] = p.pad[1] = p.pad[2] = 0;
    prm[t] = p;
}

// ---------------------------------------------------------------------------
// Kernel 1: transpose data [B=2][C=256][S=16384] -> ws [B][S][C]
// Tiles of 32 channels x 128 spatial; float4 global loads AND stores.
// ---------------------------------------------------------------------------
#define TP_SP 133   // padded LDS row stride; 133 mod 32 = 5, coprime with 32
__global__ __launch_bounds__(256) void transpose_kernel(
    const float* __restrict__ in, float* __restrict__ outp)
{
    __shared__ float tile[32 * TP_SP];
    const int b  = blockIdx.z;
    const int st = blockIdx.x * 128;
    const int ct = blockIdx.y * 32;
    const int tid = threadIdx.x;

    const float* inb  = in   + (size_t)b * 256 * 16384;
    float*       outb = outp + (size_t)b * 16384 * 256;

    {
        const int sx = (tid & 31) * 4;
        const int cy = tid >> 5;
        #pragma unroll
        for (int k = 0; k < 4; ++k) {
            const int c_local = cy + 8 * k;
            const float4 v = *(const float4*)(inb + (size_t)(ct + c_local) * 16384 + st + sx);
            float* tt = &tile[c_local * TP_SP + sx];
            tt[0] = v.x; tt[1] = v.y; tt[2] = v.z; tt[3] = v.w;
        }
    }
    __syncthreads();
    {
        const int cq = (tid & 7) * 4;
        const int sl = tid >> 3;
        #pragma unroll
        for (int k = 0; k < 4; ++k) {
            const int s_local = sl + 32 * k;
            float4 v;
            v.x = tile[(cq + 0) * TP_SP + s_local];
            v.y = tile[(cq + 1) * TP_SP + s_local];
            v.z = tile[(cq + 2) * TP_SP + s_local];
            v.w = tile[(cq + 3) * TP_SP + s_local];
            *(float4*)(outb + (size_t)(st + s_local) * 256 + ct + cq) = v;
        }
    }
}

// ---------------------------------------------------------------------------
// Kernel 2: windowed gather. One wave per (n, bin); lane t = channels 4t..4t+3.
// Reads ny*nx contiguous 1KB feature rows, applies separable weights.
// XCD-aware bijective block swizzle (1568 = 8*196) keeps each roi's window
// region L2-resident on one XCD.
// ---------------------------------------------------------------------------
__global__ __launch_bounds__(256) void dpsroi_gather_kernel(
    const float* __restrict__ dataT,       // [B][H*W][C]
    const BinParam* __restrict__ prm,
    float* __restrict__ outT)              // [n][bin][C]
{
    const int C = OUTPUT_DIM;
    const int W = 128;

    // bijective XCD swizzle: GBLOCKS = 1568 = 8 * 196
    const int bid  = blockIdx.x;
    const int bswz = (bid & 7) * (GBLOCKS / 8) + (bid >> 3);
    const int l    = bswz * 4 + (threadIdx.x >> 6);   // logical wave id
    const int lane = threadIdx.x & 63;

    const BinParam& p = prm[l];

    // register-resident weights (compile-time indexed below)
    float wx[8], wy[8];
    #pragma unroll
    for (int k = 0; k < 8; ++k) { wx[k] = p.wx[k]; wy[k] = p.wy[k]; }
    const int fx = p.fx, fy = p.fy, nx = p.nx, ny = p.ny, b = p.b;

    const float* base = dataT + ((size_t)b * (128 * 128) + (size_t)fy * W + fx) * C + 4 * lane;

    float4 acc = make_float4(0.f, 0.f, 0.f, 0.f);

    #pragma unroll
    for (int ky = 0; ky < 8; ++ky) {
        if (ky >= ny) break;                       // wave-uniform
        const float* rowp = base + (size_t)ky * W * C;
        float4 rs = make_float4(0.f, 0.f, 0.f, 0.f);
        #pragma unroll
        for (int kx = 0; kx < 8; ++kx) {
            if (kx >= nx) break;                   // wave-uniform
            const float4 v = *(const float4*)(rowp + (size_t)kx * C);
            rs.x += wx[kx] * v.x;
            rs.y += wx[kx] * v.y;
            rs.z += wx[kx] * v.z;
            rs.w += wx[kx] * v.w;
        }
        acc.x += wy[ky] * rs.x;
        acc.y += wy[ky] * rs.y;
        acc.z += wy[ky] * rs.z;
        acc.w += wy[ky] * rs.w;
    }

    // outT[l][c] — contiguous 1 KB per wave
    *(float4*)(outT + (size_t)l * C + 4 * lane) = acc;
}

// ---------------------------------------------------------------------------
// Kernel 3: remap outT [n][49][256] -> out [n][256][49]. One block per n.
// ---------------------------------------------------------------------------
__global__ __launch_bounds__(256) void remap_kernel(
    const float* __restrict__ outT, float* __restrict__ outp)
{
    __shared__ float lds[NBINS * 257];
    const int n = blockIdx.x;
    const int t = threadIdx.x;
    const int TOT = NBINS * OUTPUT_DIM;        // 12544

    const float* src = outT + (size_t)n * TOT;
    float*       dst = outp + (size_t)n * TOT;

    #pragma unroll
    for (int j = 0; j < TOT / 256; ++j) {      // 49 iters
        const int f = t + 256 * j;             // f = bin*256 + c
        lds[f + (f >> 8)] = src[f];            // lds[bin*257 + c]
    }
    __syncthreads();
    #pragma unroll
    for (int j = 0; j < TOT / 256; ++j) {
        const int o = t + 256 * j;             // o = c*49 + bin
        const int c = o / NBINS;
        const int bin = o - c * NBINS;
        dst[o] = lds[bin * 257 + c];
    }
}

// ---------------------------------------------------------------------------
// Fallback (round-0): direct gather from NCHW layout, used if ws too small.
// ---------------------------------------------------------------------------
__global__ __launch_bounds__(256) void dpsroi_kernel_direct(
    const float* __restrict__ data,
    const float* __restrict__ rois,
    const float* __restrict__ offset,
    float* __restrict__ out,
    int total)
{
    int idx = blockIdx.x * blockDim.x + threadIdx.x;
    if (idx >= total) return;

    const int P = P_OUT;
    const int C = OUTPUT_DIM;
    const int H = 128, W = 128;

    int pw = idx % P;
    int ph = (idx / P) % P;
    int c  = (idx / (P * P)) % C;
    int n  = idx / (P * P * C);

    const float* roi = rois + n * 5;
    int   b   = (int)roi[0];
    float rsw = rintf(roi[1]) * SPATIAL_SCALE - 0.5f;
    float rsh = rintf(roi[2]) * SPATIAL_SCALE - 0.5f;
    float rew = (rintf(roi[3]) + 1.0f) * SPATIAL_SCALE - 0.5f;
    float reh = (rintf(roi[4]) + 1.0f) * SPATIAL_SCALE - 0.5f;
    float rw  = fmaxf(rew - rsw, 0.1f);
    float rh  = fmaxf(reh - rsh, 0.1f);
    float binw = rw / P, binh = rh / P;
    float subw = binw / SAMPLE_PER_PART, subh = binh / SAMPLE_PER_PART;

    float tx = offset[(n * 2 + 0) * (PART_SIZE * PART_SIZE) + ph * PART_SIZE + pw] * TRANS_STD;
    float ty = offset[(n * 2 + 1) * (PART_SIZE * PART_SIZE) + ph * PART_SIZE + pw] * TRANS_STD;

    float wstart = (float)pw * binw + rsw + tx * rw;
    float hstart = (float)ph * binh + rsh + ty * rh;

    const float* dplane = data + (size_t)(b * C + c) * (H * W);

    float ssum = 0.0f, count = 0.0f;
    #pragma unroll
    for (int ihs = 0; ihs < SAMPLE_PER_PART; ++ihs) {
        float hh = hstart + (float)ihs * subh;
        #pragma unroll
        for (int iws = 0; iws < SAMPLE_PER_PART; ++iws) {
            float ww = wstart + (float)iws * subw;
            float valid = ((ww >= -0.5f) & (ww <= (float)W - 0.5f) &
                           (hh >= -0.5f) & (hh <= (float)H - 0.5f)) ? 1.0f : 0.0f;
            float wc = fminf(fmaxf(ww, 0.0f), (float)W - 1.0f);
            float hc = fminf(fmaxf(hh, 0.0f), (float)H - 1.0f);
            float y0f = floorf(hc), x0f = floorf(wc);
            float y1f = ceilf(hc),  x1f = ceilf(wc);
            float dy = hc - y0f, dx = wc - x0f;
            int y0 = (int)y0f, y1 = (int)y1f;
            int x0 = (int)x0f, x1 = (int)x1f;
            float v00 = dplane[y0 * W + x0];
            float v01 = dplane[y0 * W + x1];
            float v10 = dplane[y1 * W + x0];
            float v11 = dplane[y1 * W + x1];
            float val = (1.0f - dy) * (1.0f - dx) * v00
                      + (1.0f - dy) * dx          * v01
                      + dy          * (1.0f - dx) * v10
                      + dy          * dx          * v11;
            ssum  += val * valid;
            count += valid;
        }
    }
    out[idx] = (count > 0.0f) ? (ssum / fmaxf(count, 1.0f)) : 0.0f;
}

extern "C" void kernel_launch(void* const* d_in, const int* in_sizes, int n_in,
                              void* d_out, int out_size, void* d_ws, size_t ws_size,
                              hipStream_t stream) {
    const float* data   = (const float*)d_in[0];
    const float* rois   = (const float*)d_in[1];
    const float* offset = (const float*)d_in[2];
    float* out = (float*)d_out;

    const size_t szT = (size_t)2 * 256 * 128 * 128 * sizeof(float);   // 33.55 MB
    const size_t szO = (size_t)NWAVES * OUTPUT_DIM * sizeof(float);   //  6.42 MB
    const size_t szP = (size_t)NWAVES * sizeof(BinParam);             //  0.60 MB

    if (ws_size >= szT + szO + szP) {
        float*    dataT = (float*)d_ws;
        float*    outT  = (float*)((char*)d_ws + szT);
        BinParam* prm   = (BinParam*)((char*)d_ws + szT + szO);

        params_kernel<<<(NWAVES + 255) / 256, 256, 0, stream>>>(rois, offset, prm);

        dim3 tgrid(16384 / 128, 256 / 32, 2);
        transpose_kernel<<<tgrid, 256, 0, stream>>>(data, dataT);

        dpsroi_gather_kernel<<<GBLOCKS, 256, 0, stream>>>(dataT, prm, outT);

        remap_kernel<<<NROIS, 256, 0, stream>>>(outT, out);
    } else {
        int total = out_size;
        dpsroi_kernel_direct<<<(total + 255) / 256, 256, 0, stream>>>(data, rois, offset, out, total);
    }
}

// Round 6
// 95.723 us; speedup vs baseline: 1.7405x; 1.0985x over previous
//
#include <hip/hip_runtime.h>
#include <hip/hip_fp16.h>

#define SPATIAL_SCALE 0.0625f
#define P_OUT 7
#define OUTPUT_DIM 256
#define PART_SIZE 7
#define SAMPLE_PER_PART 4
#define TRANS_STD 0.1f

#define NROIS 128
#define NBINS (P_OUT * P_OUT)            // 49
#define NWAVES (NROIS * NBINS)           // 6272
#define GBLOCKS (NWAVES / 4)             // 1568 = 8 * 196
#define TPBLOCKS 2048                    // transpose blocks: 128 sx * 8 ct * 2 b
#define PRMBLOCKS ((NWAVES + 255) / 256) // 25

// Per-bin separable-weight parameters (96 B). wx/wy are zero outside the
// window and pre-scaled by 1/max(count,1) per axis.
struct BinParam {
    float wx[8];
    float wy[8];
    int   fx, fy;    // window origin (pixel coords), window fully in-bounds
    int   nx, ny;    // window extent (<= 8)
    int   b;
    int   pad[3];
};

// ---------------------------------------------------------------------------
// Kernel 1 (fused): blocks [0,2048) transpose data [B][C][S] -> dataT f16
// [B][S][C]; blocks [2048, 2073) compute per-bin separable weights.
// ---------------------------------------------------------------------------
#define TP_SP 133   // padded LDS row stride; 133 mod 32 = 5
__global__ __launch_bounds__(256) void prep_kernel(
    const float* __restrict__ in,
    const float* __restrict__ rois,
    const float* __restrict__ offset,
    __half* __restrict__ dataT,
    BinParam* __restrict__ prm)
{
    __shared__ float tile[32 * TP_SP];
    const int bid = blockIdx.x;

    if (bid < TPBLOCKS) {
        // ---- transpose: 32 channels x 128 spatial per block ----
        const int st = (bid & 127) * 128;        // spatial tile base
        const int ct = ((bid >> 7) & 7) * 32;    // channel tile base
        const int b  = bid >> 10;
        const int tid = threadIdx.x;

        const float* inb  = in    + (size_t)b * 256 * 16384;
        __half*      outb = dataT + (size_t)b * 16384 * 256;

        {
            const int sx = (tid & 31) * 4;
            const int cy = tid >> 5;
            #pragma unroll
            for (int k = 0; k < 4; ++k) {
                const int c_local = cy + 8 * k;
                const float4 v = *(const float4*)(inb + (size_t)(ct + c_local) * 16384 + st + sx);
                float* tt = &tile[c_local * TP_SP + sx];
                tt[0] = v.x; tt[1] = v.y; tt[2] = v.z; tt[3] = v.w;
            }
        }
        __syncthreads();
        {
            const int cq = (tid & 7) * 4;
            const int sl = tid >> 3;
            #pragma unroll
            for (int k = 0; k < 4; ++k) {
                const int s_local = sl + 32 * k;
                __half2 h0 = __floats2half2_rn(tile[(cq + 0) * TP_SP + s_local],
                                               tile[(cq + 1) * TP_SP + s_local]);
                __half2 h1 = __floats2half2_rn(tile[(cq + 2) * TP_SP + s_local],
                                               tile[(cq + 3) * TP_SP + s_local]);
                uint2 uu;
                uu.x = *reinterpret_cast<unsigned*>(&h0);
                uu.y = *reinterpret_cast<unsigned*>(&h1);
                // halves offset (st+s_local)*256 + ct+cq : byte-aligned to 8 (cq mult of 4)
                *reinterpret_cast<uint2*>(outb + (size_t)(st + s_local) * 256 + ct + cq) = uu;
            }
        }
        return;
    }

    // ---- params: one thread per (n, bin) ----
    const int t = (bid - TPBLOCKS) * 256 + threadIdx.x;
    if (t >= NWAVES) return;
    const int bin = t % NBINS;
    const int n   = t / NBINS;
    const int pw  = bin % P_OUT;
    const int ph  = bin / P_OUT;

    const float* roi = rois + n * 5;
    const int   b   = (int)roi[0];
    const float rsw = rintf(roi[1]) * SPATIAL_SCALE - 0.5f;
    const float rsh = rintf(roi[2]) * SPATIAL_SCALE - 0.5f;
    const float rew = (rintf(roi[3]) + 1.0f) * SPATIAL_SCALE - 0.5f;
    const float reh = (rintf(roi[4]) + 1.0f) * SPATIAL_SCALE - 0.5f;
    const float rw  = fmaxf(rew - rsw, 0.1f);
    const float rh  = fmaxf(reh - rsh, 0.1f);
    const float binw = rw * (1.0f / P_OUT);
    const float binh = rh * (1.0f / P_OUT);
    const float subw = binw * (1.0f / SAMPLE_PER_PART);
    const float subh = binh * (1.0f / SAMPLE_PER_PART);

    // part_h == ph, part_w == pw (P == PART_SIZE == 7, fp32-exact)
    const float tx = offset[(n * 2 + 0) * (PART_SIZE * PART_SIZE) + ph * PART_SIZE + pw] * TRANS_STD;
    const float ty = offset[(n * 2 + 1) * (PART_SIZE * PART_SIZE) + ph * PART_SIZE + pw] * TRANS_STD;

    const float wstart = (float)pw * binw + rsw + tx * rw;
    const float hstart = (float)ph * binh + rsh + ty * rh;

    BinParam p;
    // ---- x axis ----
    {
        const int F = (int)floorf(fminf(fmaxf(wstart, 0.0f), 127.0f));
        float cX = 0.0f;
        float W8[8] = {0,0,0,0,0,0,0,0};
        #pragma unroll
        for (int j = 0; j < SAMPLE_PER_PART; ++j) {
            const float w = wstart + (float)j * subw;
            const bool  v = (w >= -0.5f) && (w <= 127.5f);
            const float wc = fminf(fmaxf(w, 0.0f), 127.0f);
            const int f = (int)floorf(wc);
            const int c = (int)ceilf(wc);
            const float dx = wc - (float)f;
            if (v) {
                W8[min(max(f - F, 0), 7)] += 1.0f - dx;
                W8[min(max(c - F, 0), 7)] += dx;
                cX += 1.0f;
            }
        }
        const float wcL = fminf(fmaxf(wstart + 3.0f * subw, 0.0f), 127.0f);
        p.fx = F;
        p.nx = min((int)ceilf(wcL) - F + 1, 8);
        const float s = 1.0f / fmaxf(cX, 1.0f);
        #pragma unroll
        for (int k = 0; k < 8; ++k) p.wx[k] = W8[k] * s;
    }
    // ---- y axis ----
    {
        const int F = (int)floorf(fminf(fmaxf(hstart, 0.0f), 127.0f));
        float cY = 0.0f;
        float W8[8] = {0,0,0,0,0,0,0,0};
        #pragma unroll
        for (int j = 0; j < SAMPLE_PER_PART; ++j) {
            const float h = hstart + (float)j * subh;
            const bool  v = (h >= -0.5f) && (h <= 127.5f);
            const float hc = fminf(fmaxf(h, 0.0f), 127.0f);
            const int f = (int)floorf(hc);
            const int c = (int)ceilf(hc);
            const float dy = hc - (float)f;
            if (v) {
                W8[min(max(f - F, 0), 7)] += 1.0f - dy;
                W8[min(max(c - F, 0), 7)] += dy;
                cY += 1.0f;
            }
        }
        const float hcL = fminf(fmaxf(hstart + 3.0f * subh, 0.0f), 127.0f);
        p.fy = F;
        p.ny = min((int)ceilf(hcL) - F + 1, 8);
        const float s = 1.0f / fmaxf(cY, 1.0f);
        #pragma unroll
        for (int k = 0; k < 8; ++k) p.wy[k] = W8[k] * s;
    }
    p.b = b;
    p.pad[0] = p.pad[1] = p.pad[2] = 0;
    prm[t] = p;
}

// ---------------------------------------------------------------------------
// Kernel 2: gather + fused output remap. One wave per (n,bin); lane handles
// 8 channels (16 B f16); half-waves cover even/odd window x-pixels.
// Block = 4 consecutive bins; LDS merge + direct out[n][c][bin] stores.
// ---------------------------------------------------------------------------
__global__ __launch_bounds__(256) void gather_kernel(
    const __half* __restrict__ dataT,   // [B][H*W][C] f16
    const BinParam* __restrict__ prm,
    float* __restrict__ outp)           // [n][c][bin]
{
    __shared__ float lds[4 * 2 * 256];

    const int bid  = blockIdx.x;
    const int bswz = (bid & 7) * (GBLOCKS / 8) + (bid >> 3);   // bijective XCD swizzle
    const int w    = threadIdx.x >> 6;
    const int lane = threadIdx.x & 63;
    const int l    = bswz * 4 + w;

    const BinParam p = prm[l];

    const int half_id = lane >> 5;           // 0: even x-pixels, 1: odd
    const int c0      = (lane & 31) * 8;     // 8 channels per lane

    // per-lane x-weights with static indices (avoid dyn-indexed private array)
    float mwx[4];
    if (half_id) { mwx[0] = p.wx[1]; mwx[1] = p.wx[3]; mwx[2] = p.wx[5]; mwx[3] = p.wx[7]; }
    else         { mwx[0] = p.wx[0]; mwx[1] = p.wx[2]; mwx[2] = p.wx[4]; mwx[3] = p.wx[6]; }

    const __half* base = dataT
        + ((size_t)p.b * (128 * 128) + (size_t)p.fy * 128 + p.fx) * 256 + c0;

    float acc[8] = {0,0,0,0,0,0,0,0};

    #pragma unroll
    for (int ky = 0; ky < 8; ++ky) {
        if (ky >= p.ny) break;                              // wave-uniform
        const float wyk = p.wy[ky];                          // static index
        const __half* rowp = base + (size_t)ky * (128 * 256);
        #pragma unroll
        for (int kp = 0; kp < 4; ++kp) {
            if (2 * kp >= p.nx) break;                      // wave-uniform
            const int pxr = 2 * kp + half_id;
            const int px  = min(pxr, p.nx - 1);             // clamp addr; weight is 0 there
            const float wgt = wyk * mwx[kp];
            const uint4 u = *(const uint4*)(rowp + (size_t)px * 256);
            {
                __half2 h = *reinterpret_cast<const __half2*>(&u.x);
                float2 f = __half22float2(h);
                acc[0] += wgt * f.x; acc[1] += wgt * f.y;
            }
            {
                __half2 h = *reinterpret_cast<const __half2*>(&u.y);
                float2 f = __half22float2(h);
                acc[2] += wgt * f.x; acc[3] += wgt * f.y;
            }
            {
                __half2 h = *reinterpret_cast<const __half2*>(&u.z);
                float2 f = __half22float2(h);
                acc[4] += wgt * f.x; acc[5] += wgt * f.y;
            }
            {
                __half2 h = *reinterpret_cast<const __half2*>(&u.w);
                float2 f = __half22float2(h);
                acc[6] += wgt * f.x; acc[7] += wgt * f.y;
            }
        }
    }

    // stage partials: lds[w][half][c]
    float* myl = &lds[(w * 2 + half_id) * 256 + c0];
    #pragma unroll
    for (int k = 0; k < 8; ++k) myl[k] = acc[k];
    __syncthreads();

    // output: thread t owns channel c=t for the block's 4 bins
    const int c  = threadIdx.x;
    const int l0 = bswz * 4;
    #pragma unroll
    for (int j = 0; j < 4; ++j) {
        const int lj  = l0 + j;
        const int n   = lj / NBINS;
        const int bin = lj - n * NBINS;
        const float v = lds[(j * 2 + 0) * 256 + c] + lds[(j * 2 + 1) * 256 + c];
        outp[(size_t)n * (OUTPUT_DIM * NBINS) + (size_t)c * NBINS + bin] = v;
    }
}

// ---------------------------------------------------------------------------
// Fallback (round-0): direct gather from NCHW layout, used if ws too small.
// ---------------------------------------------------------------------------
__global__ __launch_bounds__(256) void dpsroi_kernel_direct(
    const float* __restrict__ data,
    const float* __restrict__ rois,
    const float* __restrict__ offset,
    float* __restrict__ out,
    int total)
{
    int idx = blockIdx.x * blockDim.x + threadIdx.x;
    if (idx >= total) return;

    const int P = P_OUT;
    const int C = OUTPUT_DIM;
    const int H = 128, W = 128;

    int pw = idx % P;
    int ph = (idx / P) % P;
    int c  = (idx / (P * P)) % C;
    int n  = idx / (P * P * C);

    const float* roi = rois + n * 5;
    int   b   = (int)roi[0];
    float rsw = rintf(roi[1]) * SPATIAL_SCALE - 0.5f;
    float rsh = rintf(roi[2]) * SPATIAL_SCALE - 0.5f;
    float rew = (rintf(roi[3]) + 1.0f) * SPATIAL_SCALE - 0.5f;
    float reh = (rintf(roi[4]) + 1.0f) * SPATIAL_SCALE - 0.5f;
    float rw  = fmaxf(rew - rsw, 0.1f);
    float rh  = fmaxf(reh - rsh, 0.1f);
    float binw = rw / P, binh = rh / P;
    float subw = binw / SAMPLE_PER_PART, subh = binh / SAMPLE_PER_PART;

    float tx = offset[(n * 2 + 0) * (PART_SIZE * PART_SIZE) + ph * PART_SIZE + pw] * TRANS_STD;
    float ty = offset[(n * 2 + 1) * (PART_SIZE * PART_SIZE) + ph * PART_SIZE + pw] * TRANS_STD;

    float wstart = (float)pw * binw + rsw + tx * rw;
    float hstart = (float)ph * binh + rsh + ty * rh;

    const float* dplane = data + (size_t)(b * C + c) * (H * W);

    float ssum = 0.0f, count = 0.0f;
    #pragma unroll
    for (int ihs = 0; ihs < SAMPLE_PER_PART; ++ihs) {
        float hh = hstart + (float)ihs * subh;
        #pragma unroll
        for (int iws = 0; iws < SAMPLE_PER_PART; ++iws) {
            float ww = wstart + (float)iws * subw;
            float valid = ((ww >= -0.5f) & (ww <= (float)W - 0.5f) &
                           (hh >= -0.5f) & (hh <= (float)H - 0.5f)) ? 1.0f : 0.0f;
            float wc = fminf(fmaxf(ww, 0.0f), (float)W - 1.0f);
            float hc = fminf(fmaxf(hh, 0.0f), (float)H - 1.0f);
            float y0f = floorf(hc), x0f = floorf(wc);
            float y1f = ceilf(hc),  x1f = ceilf(wc);
            float dy = hc - y0f, dx = wc - x0f;
            int y0 = (int)y0f, y1 = (int)y1f;
            int x0 = (int)x0f, x1 = (int)x1f;
            float v00 = dplane[y0 * W + x0];
            float v01 = dplane[y0 * W + x1];
            float v10 = dplane[y1 * W + x0];
            float v11 = dplane[y1 * W + x1];
            float val = (1.0f - dy) * (1.0f - dx) * v00
                      + (1.0f - dy) * dx          * v01
                      + dy          * (1.0f - dx) * v10
                      + dy          * dx          * v11;
            ssum  += val * valid;
            count += valid;
        }
    }
    out[idx] = (count > 0.0f) ? (ssum / fmaxf(count, 1.0f)) : 0.0f;
}

extern "C" void kernel_launch(void* const* d_in, const int* in_sizes, int n_in,
                              void* d_out, int out_size, void* d_ws, size_t ws_size,
                              hipStream_t stream) {
    const float* data   = (const float*)d_in[0];
    const float* rois   = (const float*)d_in[1];
    const float* offset = (const float*)d_in[2];
    float* out = (float*)d_out;

    const size_t szT = (size_t)2 * 16384 * 256 * sizeof(__half);   // 16.78 MB
    const size_t szP = (size_t)NWAVES * sizeof(BinParam);          //  0.60 MB

    if (ws_size >= szT + szP) {
        __half*   dataT = (__half*)d_ws;
        BinParam* prm   = (BinParam*)((char*)d_ws + szT);

        prep_kernel<<<TPBLOCKS + PRMBLOCKS, 256, 0, stream>>>(data, rois, offset, dataT, prm);
        gather_kernel<<<GBLOCKS, 256, 0, stream>>>(dataT, prm, out);
    } else {
        int total = out_size;
        dpsroi_kernel_direct<<<(total + 255) / 256, 256, 0, stream>>>(data, rois, offset, out, total);
    }
}